// Round 13
// baseline (4679.241 us; speedup 1.0000x reference)
//
#include <hip/hip_runtime.h>
#include <hip/hip_bf16.h>

#define DMODEL 256
#define S_TOT  70
#define BATCH  128
#define HEADS  8
#define DHEAD  32
#define PAST_N 50
#define FUT_N  20
#define LAYERS 3
#define FFD    1024

#define NT 512
// ---- decode weight stream (r11 layout, UNCHANGED): per-wave sub-tile
// sequences. Sub-tile = 256 uint4 (4KB) = 32 cols x 8 k8-groups; entry
// e = kh*128 + j*32 + col holds W[k8=st*8+kh*4+j][colbase+col] (8 f16).
// Per wave per step 192 sub-tiles: CKV 6blk*4, per layer
// [QKV 3*4 | WO 4 | CAQ 4 | CAO 4 | FF1 4*4 | FF2 1*16].
#define SUBT_W   192
#define TOTAL_ENT (8 * SUBT_W * 256)

__device__ __forceinline__ float wave_sum64(float v) {
#pragma unroll
  for (int off = 32; off > 0; off >>= 1) v += __shfl_xor(v, off, 64);
  return v;
}
__device__ __forceinline__ float wave_max64(float v) {
#pragma unroll
  for (int off = 32; off > 0; off >>= 1) v = fmaxf(v, __shfl_xor(v, off, 64));
  return v;
}
__device__ __forceinline__ float gelu_f(float x) {
  return 0.5f * x * (1.0f + erff(x * 0.7071067811865476f));
}
__device__ __forceinline__ uint16_t f2bf(float v) {
  uint32_t b = __float_as_uint(v);
  return (uint16_t)((b + 0x7fffu + ((b >> 16) & 1u)) >> 16);
}
__device__ __forceinline__ float bl16(uint32_t w) { return __uint_as_float(w << 16); }
__device__ __forceinline__ float bh16(uint32_t w) { return __uint_as_float(w & 0xffff0000u); }
__device__ __forceinline__ uint16_t f2h(float v) {
  _Float16 h = (_Float16)v;
  return __builtin_bit_cast(uint16_t, h);
}
__device__ __forceinline__ uint32_t pk2(float lo_, float hi_) {
  return ((uint32_t)f2h(hi_) << 16) | (uint32_t)f2h(lo_);
}
__device__ __forceinline__ float fdot2a(uint32_t a, uint32_t b, float acc) {
  asm("v_dot2_f32_f16 %0, %1, %2, %0" : "+v"(acc) : "v"(a), "v"(b));
  return acc;
}

#define SYNC() do { __builtin_amdgcn_sched_barrier(0); \
  asm volatile("s_waitcnt lgkmcnt(0)" ::: "memory"); \
  __builtin_amdgcn_s_barrier(); \
  __builtin_amdgcn_sched_barrier(0); } while (0)
#define VMWAIT4() do { __builtin_amdgcn_sched_barrier(0); \
  asm volatile("s_waitcnt vmcnt(4)" ::: "memory"); \
  __builtin_amdgcn_sched_barrier(0); } while (0)

__device__ __forceinline__ void gld_lds16(const uint4* g, uint4* l) {
  __builtin_amdgcn_global_load_lds(
      (const __attribute__((address_space(1))) void*)g,
      (__attribute__((address_space(3))) void*)l, 16, 0, 0);
}

__device__ __forceinline__ float ln_norm_256(float x, float g, float b, float* sbuf, int tid) {
  float s = wave_sum64(x);
  if ((tid & 63) == 0) sbuf[tid >> 6] = s;
  __syncthreads();
  float mean = (sbuf[0] + sbuf[1] + sbuf[2] + sbuf[3]) * (1.0f / 256.0f);
  __syncthreads();
  float d = x - mean;
  float vs = wave_sum64(d * d);
  if ((tid & 63) == 0) sbuf[tid >> 6] = vs;
  __syncthreads();
  float var = (sbuf[0] + sbuf[1] + sbuf[2] + sbuf[3]) * (1.0f / 256.0f);
  return d * rsqrtf(var + 1e-5f) * g + b;
}

// ======================= MFMA bf16 prefill GEMM (unchanged) =================
#define LDK 72

__global__ __launch_bounds__(256) void k_gemm_mf(
    const float* __restrict__ A, const float* __restrict__ W,
    const float* __restrict__ bias, const float* __restrict__ Rres,
    float* __restrict__ C, int M, int N, int K, int act, int outmode,
    float* __restrict__ qout, __hip_bfloat16* __restrict__ kc,
    __hip_bfloat16* __restrict__ vc, __hip_bfloat16* __restrict__ c6,
    int rows_per_b, int pos_base)
{
  typedef __attribute__((ext_vector_type(8))) short bf8;
  typedef __attribute__((ext_vector_type(4))) float f4;
  __shared__ short Al[2][128 * LDK];
  __shared__ short Bl[2][64 * LDK];
  const int tid = threadIdx.x;
  const int wv = tid >> 6, lane = tid & 63;
  const int bm0 = blockIdx.y * 128, bn0 = blockIdx.x * 64;
  const int nkt = K >> 6;
  const int ar = tid >> 1, ah = (tid & 1) << 5;
  const int br = tid >> 2, bq = (tid & 3) << 4;

  f4 acc[2][4];
#pragma unroll
  for (int i = 0; i < 2; i++)
#pragma unroll
    for (int j = 0; j < 4; j++) acc[i][j] = (f4)0.f;

  auto stage = [&](int buf, int kt) {
    const int k0 = kt << 6;
    const float* ap = A + (size_t)(bm0 + ar) * K + k0 + ah;
    float4 av[8];
#pragma unroll
    for (int u = 0; u < 8; u++) av[u] = *(const float4*)(ap + 4 * u);
    const float* wp = W + (size_t)(bn0 + br) * K + k0 + bq;
    float4 wv4[4];
#pragma unroll
    for (int u = 0; u < 4; u++) wv4[u] = *(const float4*)(wp + 4 * u);
    short* ad = &Al[buf][ar * LDK + ah];
#pragma unroll
    for (int u = 0; u < 8; u++) {
      short4 sv = {(short)f2bf(av[u].x), (short)f2bf(av[u].y),
                   (short)f2bf(av[u].z), (short)f2bf(av[u].w)};
      *(short4*)(ad + 4 * u) = sv;
    }
    short* bd = &Bl[buf][br * LDK + bq];
#pragma unroll
    for (int u = 0; u < 4; u++) {
      short4 sv = {(short)f2bf(wv4[u].x), (short)f2bf(wv4[u].y),
                   (short)f2bf(wv4[u].z), (short)f2bf(wv4[u].w)};
      *(short4*)(bd + 4 * u) = sv;
    }
  };

  auto comp = [&](int buf) {
    const int am = wv * 32 + (lane & 15);
    const int bn = lane & 15;
    const int kb = (lane >> 4) * 8;
#pragma unroll
    for (int kk = 0; kk < 2; kk++) {
      const int ko = kk * 32 + kb;
      bf8 a0 = *(const bf8*)&Al[buf][am * LDK + ko];
      bf8 a1 = *(const bf8*)&Al[buf][(am + 16) * LDK + ko];
      bf8 b0 = *(const bf8*)&Bl[buf][bn * LDK + ko];
      bf8 b1 = *(const bf8*)&Bl[buf][(bn + 16) * LDK + ko];
      bf8 b2 = *(const bf8*)&Bl[buf][(bn + 32) * LDK + ko];
      bf8 b3 = *(const bf8*)&Bl[buf][(bn + 48) * LDK + ko];
      acc[0][0] = __builtin_amdgcn_mfma_f32_16x16x32_bf16(a0, b0, acc[0][0], 0, 0, 0);
      acc[0][1] = __builtin_amdgcn_mfma_f32_16x16x32_bf16(a0, b1, acc[0][1], 0, 0, 0);
      acc[0][2] = __builtin_amdgcn_mfma_f32_16x16x32_bf16(a0, b2, acc[0][2], 0, 0, 0);
      acc[0][3] = __builtin_amdgcn_mfma_f32_16x16x32_bf16(a0, b3, acc[0][3], 0, 0, 0);
      acc[1][0] = __builtin_amdgcn_mfma_f32_16x16x32_bf16(a1, b0, acc[1][0], 0, 0, 0);
      acc[1][1] = __builtin_amdgcn_mfma_f32_16x16x32_bf16(a1, b1, acc[1][1], 0, 0, 0);
      acc[1][2] = __builtin_amdgcn_mfma_f32_16x16x32_bf16(a1, b2, acc[1][2], 0, 0, 0);
      acc[1][3] = __builtin_amdgcn_mfma_f32_16x16x32_bf16(a1, b3, acc[1][3], 0, 0, 0);
    }
  };

  stage(0, 0);
  __syncthreads();
  for (int kt = 0; kt < nkt; kt++) {
    if (kt + 1 < nkt) stage((kt & 1) ^ 1, kt + 1);
    comp(kt & 1);
    __syncthreads();
  }

  const int n0 = bn0 + (lane & 15);
  const int r0 = bm0 + wv * 32 + (lane >> 4) * 4;
#pragma unroll
  for (int i = 0; i < 2; i++) {
#pragma unroll
    for (int r = 0; r < 4; r++) {
      const int row = r0 + i * 16 + r;
      const int b = row / rows_per_b;
      const int t = pos_base + row % rows_per_b;
#pragma unroll
      for (int j = 0; j < 4; j++) {
        const int n = n0 + j * 16;
        float v = acc[i][j][r] + bias[n];
        if (Rres) v += Rres[(size_t)row * N + n];
        if (act) v = gelu_f(v);
        if (outmode == 0) {
          C[(size_t)row * N + n] = v;
        } else if (outmode == 1) {
          if (n < 256) qout[(size_t)row * DMODEL + n] = v;
          else if (n < 512) kc[((size_t)b * S_TOT + t) * DMODEL + (n - 256)] = __float2bfloat16(v);
          else vc[((size_t)b * S_TOT + t) * DMODEL + (n - 512)] = __float2bfloat16(v);
        } else {
          const int j6 = n >> 8;
          c6[(size_t)j6 * ((size_t)BATCH * S_TOT * DMODEL) +
             ((size_t)b * S_TOT + t) * DMODEL + (n & 255)] = __float2bfloat16(v);
        }
      }
    }
  }
}

// ======================= other prefill kernels (unchanged) =================
__global__ __launch_bounds__(64) void k_attn(
    const float* __restrict__ qbuf, const __hip_bfloat16* __restrict__ kc,
    const __hip_bfloat16* __restrict__ vc, float* __restrict__ outb,
    int rows_per_b, int pos_base)
{
  __shared__ float qs[DHEAD];
  __shared__ float ss[S_TOT];
  const int bid = blockIdx.x;
  const int h = bid & (HEADS - 1);
  const int row = bid >> 3;
  const int b = row / rows_per_b;
  const int t = pos_base + row % rows_per_b;
  const int nk = t + 1;
  const int lane = threadIdx.x;
  if (lane < DHEAD) qs[lane] = qbuf[(size_t)row * DMODEL + h * DHEAD + lane];
  __syncthreads();
  float mx = -1e30f;
  for (int k0 = lane; k0 < nk; k0 += 64) {
    const __hip_bfloat16* kp = kc + ((size_t)b * S_TOT + k0) * DMODEL + h * DHEAD;
    float s = 0.f;
#pragma unroll
    for (int i = 0; i < DHEAD; i++) s += qs[i] * __bfloat162float(kp[i]);
    s *= 0.17677669529663687f;
    ss[k0] = s;
    mx = fmaxf(mx, s);
  }
  mx = wave_max64(mx);
  float sum = 0.f;
  for (int k0 = lane; k0 < nk; k0 += 64) {
    float e = expf(ss[k0] - mx);
    ss[k0] = e;
    sum += e;
  }
  sum = wave_sum64(sum);
  __syncthreads();
  const float inv = 1.0f / sum;
  if (lane < DHEAD) {
    float o = 0.f;
    for (int k0 = 0; k0 < nk; k0++)
      o += ss[k0] * __bfloat162float(vc[((size_t)b * S_TOT + k0) * DMODEL + h * DHEAD + lane]);
    outb[(size_t)row * DMODEL + h * DHEAD + lane] = o * inv;
  }
}

__global__ __launch_bounds__(256) void k_ln(
    const float* __restrict__ Z, const float* __restrict__ g,
    const float* __restrict__ b, float* __restrict__ out)
{
  __shared__ float sbuf[4];
  const int row = blockIdx.x, tid = threadIdx.x;
  float x = Z[(size_t)row * DMODEL + tid];
  out[(size_t)row * DMODEL + tid] = ln_norm_256(x, g[tid], b[tid], sbuf, tid);
}

__global__ __launch_bounds__(256) void k_embed(
    const float* __restrict__ past, const float* __restrict__ in_W,
    const float* __restrict__ in_b, const float* __restrict__ pos_emb,
    const float* __restrict__ ln_w, const float* __restrict__ ln_b,
    float* __restrict__ Aout)
{
  __shared__ float sbuf[4];
  const int rowid = blockIdx.x;
  const int b = rowid / PAST_N, t = rowid % PAST_N;
  const int tid = threadIdx.x;
  float dx = 0.f, dy = 0.f;
  if (t > 0) {
    dx = past[((size_t)b * PAST_N + t) * 2 + 0] - past[((size_t)b * PAST_N + t - 1) * 2 + 0];
    dy = past[((size_t)b * PAST_N + t) * 2 + 1] - past[((size_t)b * PAST_N + t - 1) * 2 + 1];
  }
  float v = in_W[tid * 2 + 0] * dx + in_W[tid * 2 + 1] * dy + in_b[tid] +
            pos_emb[(size_t)t * DMODEL + tid];
  Aout[(size_t)rowid * DMODEL + tid] = ln_norm_256(v, ln_w[tid], ln_b[tid], sbuf, tid);
}

__global__ __launch_bounds__(256) void k_prepack(
    const float* __restrict__ caW, const float* __restrict__ cab,
    float* __restrict__ Wckv, float* __restrict__ bckv)
{
  const int n = blockIdx.x, tid = threadIdx.x;
  const int j = n >> 8, dcol = n & 255;
  const int l = j >> 1, kv = j & 1;
  const int srow = l * 768 + 256 + kv * 256 + dcol;
  Wckv[(size_t)n * 256 + tid] = caW[(size_t)srow * 256 + tid];
  if (tid == 0) bckv[n] = cab[l * 768 + 256 + kv * 256 + dcol];
}

__global__ __launch_bounds__(64) void k_readout(
    const float* __restrict__ X, const float* __restrict__ out_W,
    const float* __restrict__ out_b, const float* __restrict__ past,
    float* __restrict__ cur, float* __restrict__ ndb, float* __restrict__ out,
    int rows_per_b, int s, int init)
{
  const int b = blockIdx.x, lane = threadIdx.x;
  const int row = b * rows_per_b + rows_per_b - 1;
  float p0 = 0.f, p1 = 0.f;
  for (int d = lane; d < DMODEL; d += 64) {
    const float xv = X[(size_t)row * DMODEL + d];
    p0 += xv * out_W[d];
    p1 += xv * out_W[DMODEL + d];
  }
  p0 = wave_sum64(p0);
  p1 = wave_sum64(p1);
  if (lane == 0) {
    const float nd0 = p0 + out_b[0];
    const float nd1 = p1 + out_b[1];
    float c0, c1;
    if (init) {
      c0 = past[((size_t)b * PAST_N + PAST_N - 1) * 2 + 0];
      c1 = past[((size_t)b * PAST_N + PAST_N - 1) * 2 + 1];
    } else {
      c0 = cur[b * 2 + 0];
      c1 = cur[b * 2 + 1];
    }
    c0 += nd0; c1 += nd1;
    cur[b * 2 + 0] = c0; cur[b * 2 + 1] = c1;
    ndb[b * 2 + 0] = nd0; ndb[b * 2 + 1] = nd1;
    out[((size_t)b * FUT_N + s) * 2 + 0] = c0;
    out[((size_t)b * FUT_N + s) * 2 + 1] = c1;
  }
}

// ======================= decode stream pack (r11, unchanged) ===============
__global__ __launch_bounds__(256) void k_pack_stream(
    const float* __restrict__ sa_Wqkv, const float* __restrict__ sa_Wo,
    const float* __restrict__ ca_Wqkv, const float* __restrict__ ca_Wo,
    const float* __restrict__ ff1_W, const float* __restrict__ ff2_W,
    uint4* __restrict__ Wd)
{
  const unsigned gidx = blockIdx.x * 256 + threadIdx.x;
  if (gidx >= TOTAL_ENT) return;
  const unsigned w = gidx / (SUBT_W * 256);
  const unsigned r = gidx % (SUBT_W * 256);
  const unsigned n = r >> 8, e = r & 255u;
  const int kh = e >> 7, j = (e >> 5) & 3, c = e & 31;
  const int k8l = kh * 4 + j;
  const float* src;
  if (n < 24) {
    const int blk = n >> 2, st = n & 3;
    const int col = (int)(w * 192 + blk * 32 + c);
    const int k8 = st * 8 + k8l;
    const int j6 = col >> 8, dcol = col & 255, lq = j6 >> 1, kv = j6 & 1;
    src = ca_Wqkv + (size_t)lq * 196608 + (size_t)(256 + kv * 256 + dcol) * 256 + 8 * k8;
  } else {
    const unsigned m = n - 24;
    const int l = m / 56, p = m % 56;
    if (p < 12) {
      const int blk = p >> 2, st = p & 3;
      const int col = w * 96 + blk * 32 + c;
      const int k8 = st * 8 + k8l;
      src = sa_Wqkv + (size_t)l * 196608 + (size_t)col * 256 + 8 * k8;
    } else if (p < 16) {
      const int st = p - 12;
      const int col = w * 32 + c;
      const int k8 = st * 8 + k8l;
      src = sa_Wo + (size_t)l * 65536 + (size_t)col * 256 + 8 * k8;
    } else if (p < 20) {
      const int st = p - 16;
      const int col = w * 32 + c;
      const int k8 = st * 8 + k8l;
      src = ca_Wqkv + (size_t)l * 196608 + (size_t)col * 256 + 8 * k8;
    } else if (p < 24) {
      const int st = p - 20;
      const int col = w * 32 + c;
      const int k8 = st * 8 + k8l;
      src = ca_Wo + (size_t)l * 65536 + (size_t)col * 256 + 8 * k8;
    } else if (p < 40) {
      const int pp = p - 24;
      const int blk = pp >> 2, st = pp & 3;
      const int col = w * 128 + blk * 32 + c;
      const int k8 = st * 8 + k8l;
      src = ff1_W + (size_t)l * 262144 + (size_t)col * 256 + 8 * k8;
    } else {
      const int st = p - 40;
      const int col = w * 32 + c;
      const int k8 = st * 8 + k8l;
      src = ff2_W + (size_t)l * 262144 + (size_t)col * 1024 + 8 * k8;
    }
  }
  uint4 u;
  u.x = ((uint32_t)f2h(src[1]) << 16) | (uint32_t)f2h(src[0]);
  u.y = ((uint32_t)f2h(src[3]) << 16) | (uint32_t)f2h(src[2]);
  u.z = ((uint32_t)f2h(src[5]) << 16) | (uint32_t)f2h(src[4]);
  u.w = ((uint32_t)f2h(src[7]) << 16) | (uint32_t)f2h(src[6]);
  Wd[gidx] = u;
}

// ======================= fused 19-step decode: 2 batches per WG ============
// r11 ring transport (3 slots x 4KB per wave, per-wave vmcnt pipeline) with
// TWO batch elements per WG: each weight sub-tile feeds two GEMV dot
// products. Lanes 0-255 = batch0 / 256-511 = batch1 in elementwise phases.
__global__ __launch_bounds__(NT) void k_decode(
    const uint4* __restrict__ Wd, const float* __restrict__ bckv,
    const float* __restrict__ in_W, const float* __restrict__ in_b,
    const float* __restrict__ pos_emb,
    const float* __restrict__ ln0_w, const float* __restrict__ ln0_b,
    const float* __restrict__ sa_bqkv, const float* __restrict__ sa_bo,
    const float* __restrict__ ca_bqkv, const float* __restrict__ ca_bo,
    const float* __restrict__ ff1_b, const float* __restrict__ ff2_b,
    const float* __restrict__ ln1_w, const float* __restrict__ ln1_b,
    const float* __restrict__ ln2_w, const float* __restrict__ ln2_b,
    const float* __restrict__ ln3_w, const float* __restrict__ ln3_b,
    const float* __restrict__ out_W, const float* __restrict__ out_b,
    __hip_bfloat16* __restrict__ Ksa, __hip_bfloat16* __restrict__ Vsa,
    __hip_bfloat16* __restrict__ C6,
    const float* __restrict__ ndb, const float* __restrict__ cur,
    float* __restrict__ out)
{
  const int tid = threadIdx.x;
  const int wv = tid >> 6, lane = tid & 63;
  const int eb = tid >> 8, et = tid & 255;
  const int b0 = blockIdx.x << 1;
  const int sv = (wv + blockIdx.x) & 7;
  const size_t slab = (size_t)BATCH * S_TOT * DMODEL;

  __shared__ __align__(16) uint4 ring[8 * 3 * 256];   // 96 KB
  __shared__ __align__(16) float x2[2][256];
  __shared__ __align__(16) float xt2[2][256];
  __shared__ __align__(16) float q2[2][256];
  __shared__ __align__(16) float hbuf2[2][1024];
  __shared__ __align__(16) float pred2[2][256];
  __shared__ __align__(16) float kn2[2][256], vn2[2][256];
  __shared__ __align__(16) float ckvn2[2][1536];
  __shared__ __align__(16) uint32_t xhh[2][128], xthh[2][128], atth2[2][128], hh2[2][512];
  __shared__ float ss2[2][8][72];
  __shared__ float sb[8], sb2v[8];
  __shared__ float ndc[8];

  // ---- preload per-et constants to registers (identical in both halves) ----
  const float c_inW0 = in_W[2 * et], c_inW1 = in_W[2 * et + 1], c_inb = in_b[et];
  const float c_l0w = ln0_w[et], c_l0b = ln0_b[et];
  float c_bk[6];
#pragma unroll
  for (int d = 0; d < 6; d++) c_bk[d] = bckv[et + 256 * d];
  float bqq[LAYERS], bqk[LAYERS], bqv[LAYERS], bso[LAYERS], bcq[LAYERS], bco[LAYERS];
  float bf1_0[LAYERS], bf1_1[LAYERS], bf1_2[LAYERS], bf1_3[LAYERS], bf2v[LAYERS];
  float w1[LAYERS], bb1[LAYERS], w2[LAYERS], bb2[LAYERS], w3[LAYERS], bb3[LAYERS];
#pragma unroll
  for (int l = 0; l < LAYERS; l++) {
    bqq[l] = sa_bqkv[l * 768 + et];
    bqk[l] = sa_bqkv[l * 768 + 256 + et];
    bqv[l] = sa_bqkv[l * 768 + 512 + et];
    bso[l] = sa_bo[l * 256 + et];
    bcq[l] = ca_bqkv[l * 768 + et];
    bco[l] = ca_bo[l * 256 + et];
    bf1_0[l] = ff1_b[l * 1024 + et];
    bf1_1[l] = ff1_b[l * 1024 + 256 + et];
    bf1_2[l] = ff1_b[l * 1024 + 512 + et];
    bf1_3[l] = ff1_b[l * 1024 + 768 + et];
    bf2v[l] = ff2_b[l * 256 + et];
    w1[l] = ln1_w[l * 256 + et];  bb1[l] = ln1_b[l * 256 + et];
    w2[l] = ln2_w[l * 256 + et];  bb2[l] = ln2_b[l * 256 + et];
    w3[l] = ln3_w[l * 256 + et];  bb3[l] = ln3_b[l * 256 + et];
  }
  // readout consts: waves 0..3 -> (batch wv>>1, component wv&1)
  float c_ow[4] = {0.f, 0.f, 0.f, 0.f};
  float c_ob = 0.f;
  if (tid < 256) {
    const int d0 = wv & 1;
#pragma unroll
    for (int j = 0; j < 4; j++) c_ow[j] = out_W[d0 * 256 + lane + 64 * j];
    c_ob = out_b[d0];
  }
  if (tid < 2) {
    const int bb = b0 + tid;
    ndc[tid * 4 + 0] = ndb[2 * bb];     ndc[tid * 4 + 1] = ndb[2 * bb + 1];
    ndc[tid * 4 + 2] = cur[2 * bb];     ndc[tid * 4 + 3] = cur[2 * bb + 1];
  }
  asm volatile("s_waitcnt vmcnt(0)" ::: "memory");
  __syncthreads();

  auto issue = [&](unsigned g) {
    const unsigned sidx = g % (unsigned)SUBT_W;
    const unsigned slot = g % 3u;
    const uint4* src = Wd + (((size_t)sv * SUBT_W + sidx) << 8) + lane;
    uint4* dst = &ring[((unsigned)wv * 3u + slot) * 256u + (unsigned)lane];
#pragma unroll
    for (int j = 0; j < 4; j++) gld_lds16(src + (j << 6), dst + (j << 6));
  };

  // dual-batch block GEMV (r11 indexing): per sub-tile, one W read feeds TWO
  // dot products (batch0, batch1). ONE shfl per block per batch.
  auto gemvB = [&](unsigned& g, int nblk, int nst,
                   const uint4* xpA, const uint4* xpB, auto&& emit) {
    const int kh = lane >> 5, c = lane & 31;
    for (int bi = 0; bi < nblk; bi++) {
      float aA = 0.f, aB = 0.f;
      for (int st = 0; st < nst; st++) {
        VMWAIT4();
        issue(g + 2);
        const uint4* S = &ring[((unsigned)wv * 3u + (g % 3u)) * 256u] + kh * 128 + c;
        const uint4 W0 = S[0], W1 = S[32], W2 = S[64], W3 = S[96];
        const int kb = st * 8 + kh * 4;
        {
          const uint4 X0 = xpA[kb], X1 = xpA[kb + 1], X2 = xpA[kb + 2], X3 = xpA[kb + 3];
          aA = fdot2a(W0.x, X0.x, aA); aA = fdot2a(W0.y, X0.y, aA);
          aA = fdot2a(W0.z, X0.z, aA); aA = fdot2a(W0.w, X0.w, aA);
          aA = fdot2a(W1.x, X1.x, aA); aA = fdot2a(W1.y, X1.y, aA);
          aA = fdot2a(W1.z, X1.z, aA); aA = fdot2a(W1.w, X1.w, aA);
          aA = fdot2a(W2.x, X2.x, aA); aA = fdot2a(W2.y, X2.y, aA);
          aA = fdot2a(W2.z, X2.z, aA); aA = fdot2a(W2.w, X2.w, aA);
          aA = fdot2a(W3.x, X3.x, aA); aA = fdot2a(W3.y, X3.y, aA);
          aA = fdot2a(W3.z, X3.z, aA); aA = fdot2a(W3.w, X3.w, aA);
        }
        {
          const uint4 X0 = xpB[kb], X1 = xpB[kb + 1], X2 = xpB[kb + 2], X3 = xpB[kb + 3];
          aB = fdot2a(W0.x, X0.x, aB); aB = fdot2a(W0.y, X0.y, aB);
          aB = fdot2a(W0.z, X0.z, aB); aB = fdot2a(W0.w, X0.w, aB);
          aB = fdot2a(W1.x, X1.x, aB); aB = fdot2a(W1.y, X1.y, aB);
          aB = fdot2a(W1.z, X1.z, aB); aB = fdot2a(W1.w, X1.w, aB);
          aB = fdot2a(W2.x, X2.x, aB); aB = fdot2a(W2.y, X2.y, aB);
          aB = fdot2a(W2.z, X2.z, aB); aB = fdot2a(W2.w, X2.w, aB);
          aB = fdot2a(W3.x, X3.x, aB); aB = fdot2a(W3.y, X3.y, aB);
          aB = fdot2a(W3.z, X3.z, aB); aB = fdot2a(W3.w, X3.w, aB);
        }
        g++;
      }
      aA += __shfl_xor(aA, 32, 64);
      aB += __shfl_xor(aB, 32, 64);
      if (lane < 32) emit(bi * 32 + c, aA, aB);
    }
  };

  // LN over each 256-half (batch eb); stores f32 + packed-f16 mirror
  auto ln_store2 = [&](float v, float gw_, float gb_,
                       float (*dstx)[256], uint32_t (*dsth)[128]) {
    float s  = wave_sum64(v);
    float s2 = wave_sum64(v * v);
    if (lane == 0) { sb[wv] = s; sb2v[wv] = s2; }
    SYNC();
    const int base = wv & 4;
    float mean = (sb[base] + sb[base + 1] + sb[base + 2] + sb[base + 3]) * (1.0f / 256.0f);
    float ex2  = (sb2v[base] + sb2v[base + 1] + sb2v[base + 2] + sb2v[base + 3]) * (1.0f / 256.0f);
    float var = ex2 - mean * mean;
    float vn_ = (v - mean) * rsqrtf(var + 1e-5f) * gw_ + gb_;
    float vo = __shfl_xor(vn_, 1, 64);
    dstx[eb][et] = vn_;
    if (!(et & 1)) dsth[eb][et >> 1] = pk2(vn_, vo);
    SYNC();
  };

  // attention for batch ebb: 1 wave = 1 head (r11 structure)
  auto attn8 = [&](int ebb, const __hip_bfloat16* Kc, const __hip_bfloat16* Vc,
                   const float* knw, const float* vnw, int pos) {
    const int h = wv;
    const int bb = b0 + ebb;
    const float* qh = &q2[ebb][h * 32];
    float* ssr = ss2[ebb][h];
    float mx = -1e30f;
    for (int k0 = lane; k0 <= pos; k0 += 64) {
      float s = 0.f;
      if (k0 == pos) {
        const float* kp = knw + h * 32;
#pragma unroll
        for (int i = 0; i < 32; i++) s += qh[i] * kp[i];
      } else {
        const uint32_t* kp = (const uint32_t*)(Kc + ((size_t)bb * S_TOT + k0) * DMODEL + h * 32);
#pragma unroll
        for (int i = 0; i < 16; i++) {
          uint32_t w = kp[i];
          s += bl16(w) * qh[2 * i];
          s += bh16(w) * qh[2 * i + 1];
        }
      }
      s *= 0.17677669529663687f;
      ssr[k0] = s;
      mx = fmaxf(mx, s);
    }
    mx = wave_max64(mx);
    float sum = 0.f;
    for (int k0 = lane; k0 <= pos; k0 += 64) {
      float e = __expf(ssr[k0] - mx);
      ssr[k0] = e;
      sum += e;
    }
    sum = wave_sum64(sum);
    const float inv = 1.0f / sum;
    const int kpar = lane >> 4, d2 = lane & 15;
    const uint32_t* vbase = (const uint32_t*)(Vc + (size_t)bb * S_TOT * DMODEL + h * 32) + d2;
    float oA = 0.f, oB = 0.f;
    for (int k0 = kpar; k0 < pos; k0 += 4) {
      const uint32_t w = vbase[(size_t)k0 * (DMODEL / 2)];
      const float p = ssr[k0];
      oA += p * bl16(w);
      oB += p * bh16(w);
    }
    oA += __shfl_xor(oA, 16, 64); oA += __shfl_xor(oA, 32, 64);
    oB += __shfl_xor(oB, 16, 64); oB += __shfl_xor(oB, 32, 64);
    if (kpar == 0) {
      const float p = ssr[pos];
      oA += p * vnw[h * 32 + 2 * d2];
      oB += p * vnw[h * 32 + 2 * d2 + 1];
      atth2[ebb][h * 16 + d2] = pk2(oA * inv, oB * inv);
    }
  };

  unsigned g = 0;
  issue(0); issue(1);

  for (int s = 1; s < FUT_N; s++) {
    const int pos = PAST_N - 1 + s;

    // 1. token embed + LN0 -> xt2/xthh ; copy to x2/xhh
    float xe = c_inW0 * ndc[eb * 4 + 0] + c_inW1 * ndc[eb * 4 + 1] + c_inb +
               pos_emb[(size_t)pos * DMODEL + et];
    ln_store2(xe, c_l0w, c_l0b, xt2, xthh);
    x2[eb][et] = xt2[eb][et];
    if (et < 128) xhh[eb][et] = xthh[eb][et];

    // 2. CKV: 6 blocks x 4, inputs xthh[0], xthh[1]
    gemvB(g, 6, 4, (const uint4*)xthh[0], (const uint4*)xthh[1],
          [&](int cl, float aA, float aB) {
            ckvn2[0][sv * 192 + cl] = aA;
            ckvn2[1][sv * 192 + cl] = aB;
          });
    SYNC();
    {
#pragma unroll
      for (int d = 0; d < 6; d++) {
        const int n = et + 256 * d;
        float v = ckvn2[eb][n] + c_bk[d];
        ckvn2[eb][n] = v;
        C6[(size_t)d * slab + ((size_t)(b0 + eb) * S_TOT + pos) * DMODEL + et] = __float2bfloat16(v);
      }
      SYNC();
    }

#pragma unroll
    for (int l = 0; l < LAYERS; l++) {
      // a. QKV: 3 blocks x 4, inputs xhh
      gemvB(g, 3, 4, (const uint4*)xhh[0], (const uint4*)xhh[1],
            [&](int cl, float aA, float aB) {
              const int col = sv * 96 + cl;
              if (col < 256) { q2[0][col] = aA; q2[1][col] = aB; }
              else if (col < 512) { kn2[0][col - 256] = aA; kn2[1][col - 256] = aB; }
              else { vn2[0][col - 512] = aA; vn2[1][col - 512] = aB; }
            });
      SYNC();
      {
        q2[eb][et] += bqq[l];
        float kv2 = kn2[eb][et] + bqk[l];
        kn2[eb][et] = kv2;
        Ksa[(size_t)l * slab + ((size_t)(b0 + eb) * S_TOT + pos) * DMODEL + et] = __float2bfloat16(kv2);
        float vv2 = vn2[eb][et] + bqv[l];
        vn2[eb][et] = vv2;
        Vsa[(size_t)l * slab + ((size_t)(b0 + eb) * S_TOT + pos) * DMODEL + et] = __float2bfloat16(vv2);
        SYNC();
      }
      // b. SA attention (both batches, serial per wave)
      attn8(0, Ksa + (size_t)l * slab, Vsa + (size_t)l * slab, kn2[0], vn2[0], pos);
      attn8(1, Ksa + (size_t)l * slab, Vsa + (size_t)l * slab, kn2[1], vn2[1], pos);
      SYNC();
      // c. WO: 1 block x 4, inputs atth2
      gemvB(g, 1, 4, (const uint4*)atth2[0], (const uint4*)atth2[1],
            [&](int cl, float aA, float aB) {
              pred2[0][sv * 32 + cl] = aA; pred2[1][sv * 32 + cl] = aB;
            });
      SYNC();
      ln_store2(x2[eb][et] + pred2[eb][et] + bso[l], w1[l], bb1[l], x2, xhh);
      // d. CAQ: 1 block x 4, inputs xhh
      gemvB(g, 1, 4, (const uint4*)xhh[0], (const uint4*)xhh[1],
            [&](int cl, float aA, float aB) {
              pred2[0][sv * 32 + cl] = aA; pred2[1][sv * 32 + cl] = aB;
            });
      SYNC();
      q2[eb][et] = pred2[eb][et] + bcq[l];
      SYNC();
      // e. CA attention
      attn8(0, C6 + (size_t)(2 * l) * slab, C6 + (size_t)(2 * l + 1) * slab,
            &ckvn2[0][l * 512], &ckvn2[0][l * 512 + 256], pos);
      attn8(1, C6 + (size_t)(2 * l) * slab, C6 + (size_t)(2 * l + 1) * slab,
            &ckvn2[1][l * 512], &ckvn2[1][l * 512 + 256], pos);
      SYNC();
      // f. CAO: 1 block x 4, inputs atth2
      gemvB(g, 1, 4, (const uint4*)atth2[0], (const uint4*)atth2[1],
            [&](int cl, float aA, float aB) {
              pred2[0][sv * 32 + cl] = aA; pred2[1][sv * 32 + cl] = aB;
            });
      SYNC();
      ln_store2(x2[eb][et] + pred2[eb][et] + bco[l], w2[l], bb2[l], x2, xhh);
      // g. FF1: 4 blocks x 4, inputs xhh
      gemvB(g, 4, 4, (const uint4*)xhh[0], (const uint4*)xhh[1],
            [&](int cl, float aA, float aB) {
              hbuf2[0][sv * 128 + cl] = aA; hbuf2[1][sv * 128 + cl] = aB;
            });
      SYNC();
      {
        float g0 = gelu_f(hbuf2[eb][et] + bf1_0[l]);
        float g1 = gelu_f(hbuf2[eb][et + 256] + bf1_1[l]);
        float g2 = gelu_f(hbuf2[eb][et + 512] + bf1_2[l]);
        float g3 = gelu_f(hbuf2[eb][et + 768] + bf1_3[l]);
        float o0 = __shfl_xor(g0, 1, 64);
        float o1 = __shfl_xor(g1, 1, 64);
        float o2 = __shfl_xor(g2, 1, 64);
        float o3 = __shfl_xor(g3, 1, 64);
        if (!(et & 1)) {
          hh2[eb][(et) >> 1]       = pk2(g0, o0);
          hh2[eb][(et + 256) >> 1] = pk2(g1, o1);
          hh2[eb][(et + 512) >> 1] = pk2(g2, o2);
          hh2[eb][(et + 768) >> 1] = pk2(g3, o3);
        }
        SYNC();
      }
      // h. FF2: 1 block x 16 (K=1024), inputs hh2
      gemvB(g, 1, 16, (const uint4*)hh2[0], (const uint4*)hh2[1],
            [&](int cl, float aA, float aB) {
              pred2[0][sv * 32 + cl] = aA; pred2[1][sv * 32 + cl] = aB;
            });
      SYNC();
      ln_store2(x2[eb][et] + pred2[eb][et] + bf2v[l], w3[l], bb3[l], x2, xhh);
    }

    // readout: waves 0..3 -> (batch wv>>1, component wv&1)
    {
      if (tid < 256) {
        const int eb_r = wv >> 1, d0 = wv & 1;
        float p = 0.f;
#pragma unroll
        for (int j = 0; j < 4; j++) p += x2[eb_r][lane + 64 * j] * c_ow[j];
        p = wave_sum64(p);
        if (lane == 0) {
          const float nd = p + c_ob;
          ndc[eb_r * 4 + d0] = nd;
          const float c = ndc[eb_r * 4 + 2 + d0] + nd;
          ndc[eb_r * 4 + 2 + d0] = c;
          out[((size_t)(b0 + eb_r) * FUT_N + s) * 2 + d0] = c;
        }
      }
      SYNC();
    }
  }
  asm volatile("s_waitcnt vmcnt(0)" ::: "memory");
}

// ======================= host launch =======================
extern "C" void kernel_launch(void* const* d_in, const int* in_sizes, int n_in,
                              void* d_out, int out_size, void* d_ws, size_t ws_size,
                              hipStream_t stream)
{
  const float* past    = (const float*)d_in[0];
  const float* in_W    = (const float*)d_in[1];
  const float* in_b    = (const float*)d_in[2];
  const float* pos_emb = (const float*)d_in[3];
  const float* ln0_w   = (const float*)d_in[4];
  const float* ln0_b   = (const float*)d_in[5];
  const float* sa_Wqkv = (const float*)d_in[6];
  const float* sa_bqkv = (const float*)d_in[7];
  const float* sa_Wo   = (const float*)d_in[8];
  const float* sa_bo   = (const float*)d_in[9];
  const float* ca_Wqkv = (const float*)d_in[10];
  const float* ca_bqkv = (const float*)d_in[11];
  const float* ca_Wo   = (const float*)d_in[12];
  const float* ca_bo   = (const float*)d_in[13];
  const float* ff1_W   = (const float*)d_in[14];
  const float* ff1_b   = (const float*)d_in[15];
  const float* ff2_W   = (const float*)d_in[16];
  const float* ff2_b   = (const float*)d_in[17];
  const float* ln1_w   = (const float*)d_in[18];
  const float* ln1_b   = (const float*)d_in[19];
  const float* ln2_w   = (const float*)d_in[20];
  const float* ln2_b   = (const float*)d_in[21];
  const float* ln3_w   = (const float*)d_in[22];
  const float* ln3_b   = (const float*)d_in[23];
  const float* out_W   = (const float*)d_in[24];
  const float* out_b   = (const float*)d_in[25];
  float* out = (float*)d_out;

  const size_t Mpre = (size_t)BATCH * PAST_N;              // 6400
  const size_t slab = (size_t)BATCH * S_TOT * DMODEL;      // 2,293,760

  float* ws_f = (float*)d_ws;
  float* A    = ws_f;
  float* Bb   = A + Mpre * DMODEL;
  float* qb   = Bb + Mpre * DMODEL;
  float* at   = qb + Mpre * DMODEL;
  float* hb   = at + Mpre * DMODEL;
  float* Wckv = hb + Mpre * FFD;
  float* bckv = Wckv + (size_t)1536 * 256;
  float* ndb  = bckv + 1536;
  float* cur  = ndb + 256;
  __hip_bfloat16* Ksa = (__hip_bfloat16*)(cur + 256);
  __hip_bfloat16* Vsa = Ksa + 3 * slab;
  __hip_bfloat16* C6  = Vsa + 3 * slab;
  uint4* Wd = (uint4*)A;  // decode stream aliases A (dead after prefill)

  const size_t need = ((size_t)(C6 + 6 * slab) - (size_t)d_ws);
  if (ws_size < need) return;

  auto layer = [&](int l, int M, int rpb, int pbase) {
    const float* Wqkv = sa_Wqkv + (size_t)l * 768 * 256;
    __hip_bfloat16* kcl = Ksa + (size_t)l * slab;
    __hip_bfloat16* vcl = Vsa + (size_t)l * slab;
    k_gemm_mf<<<dim3(768 / 64, M / 128), 256, 0, stream>>>(
        A, Wqkv, sa_bqkv + l * 768, nullptr, nullptr, M, 768, 256, 0, 1,
        qb, kcl, vcl, nullptr, rpb, pbase);
    k_attn<<<M * HEADS, 64, 0, stream>>>(qb, kcl, vcl, at, rpb, pbase);
    k_gemm_mf<<<dim3(256 / 64, M / 128), 256, 0, stream>>>(
        at, sa_Wo + (size_t)l * 65536, sa_bo + l * 256, A, Bb, M, 256, 256, 0, 0,
        nullptr, nullptr, nullptr, nullptr, 1, 0);
    k_ln<<<M, 256, 0, stream>>>(Bb, ln1_w + l * 256, ln1_b + l * 256, A);
    k_gemm_mf<<<dim3(256 / 64, M / 128), 256, 0, stream>>>(
        A, ca_Wqkv + (size_t)l * 768 * 256, ca_bqkv + l * 768, nullptr, qb,
        M, 256, 256, 0, 0, nullptr, nullptr, nullptr, nullptr, 1, 0);
    k_attn<<<M * HEADS, 64, 0, stream>>>(
        qb, C6 + (size_t)(2 * l) * slab, C6 + (size_t)(2 * l + 1) * slab, at, rpb, pbase);
    k_gemm_mf<<<dim3(256 / 64, M / 128), 256, 0, stream>>>(
        at, ca_Wo + (size_t)l * 65536, ca_bo + l * 256, A, Bb, M, 256, 256, 0, 0,
        nullptr, nullptr, nullptr, nullptr, 1, 0);
    k_ln<<<M, 256, 0, stream>>>(Bb, ln2_w + l * 256, ln2_b + l * 256, A);
    k_gemm_mf<<<dim3(FFD / 64, M / 128), 256, 0, stream>>>(
        A, ff1_W + (size_t)l * FFD * 256, ff1_b + l * FFD, nullptr, hb,
        M, FFD, 256, 1, 0, nullptr, nullptr, nullptr, nullptr, 1, 0);
    k_gemm_mf<<<dim3(256 / 64, M / 128), 256, 0, stream>>>(
        hb, ff2_W + (size_t)l * 256 * FFD, ff2_b + l * 256, A, Bb, M, 256, FFD, 0, 0,
        nullptr, nullptr, nullptr, nullptr, 1, 0);
    k_ln<<<M, 256, 0, stream>>>(Bb, ln3_w + l * 256, ln3_b + l * 256, A);
  };

  // ---- prefill over past 50 positions ----
  k_prepack<<<1536, 256, 0, stream>>>(ca_Wqkv, ca_bqkv, Wckv, bckv);
  k_embed<<<(int)Mpre, 256, 0, stream>>>(past, in_W, in_b, pos_emb, ln0_w, ln0_b, A);
  k_gemm_mf<<<dim3(1536 / 64, (int)Mpre / 128), 256, 0, stream>>>(
      A, Wckv, bckv, nullptr, nullptr, (int)Mpre, 1536, 256, 0, 2,
      nullptr, nullptr, nullptr, C6, PAST_N, 0);
  for (int l = 0; l < LAYERS; l++) layer(l, (int)Mpre, PAST_N, 0);
  k_readout<<<BATCH, 64, 0, stream>>>(A, out_W, out_b, past, cur, ndb, out, PAST_N, 0, 1);

  // ---- pack decode weight stream (into A scratch, dead after prefill) ----
  k_pack_stream<<<(TOTAL_ENT + 255) / 256, 256, 0, stream>>>(
      sa_Wqkv, sa_Wo, ca_Wqkv, ca_Wo, ff1_W, ff2_W, Wd);

  // ---- fused 19-step decode: one WG per TWO batch elements ----
  k_decode<<<BATCH / 2, NT, 0, stream>>>(
      Wd, bckv, in_W, in_b, pos_emb, ln0_w, ln0_b,
      sa_bqkv, sa_bo, ca_bqkv, ca_bo, ff1_b, ff2_b,
      ln1_w, ln1_b, ln2_w, ln2_b, ln3_w, ln3_b,
      out_W, out_b, Ksa, Vsa, C6, ndb, cur, out);
}

// Round 15
// 3412.019 us; speedup vs baseline: 1.3714x; 1.3714x over previous
//
#include <hip/hip_runtime.h>
#include <hip/hip_bf16.h>

#define DMODEL 256
#define S_TOT  70
#define BATCH  128
#define HEADS  8
#define DHEAD  32
#define PAST_N 50
#define FUT_N  20
#define LAYERS 3
#define FFD    1024

#define NT 512
// ---- decode weight stream: per-wave sub-tile sequences. Sub-tile = 256 uint4
// (4KB) = 32 cols x 8 k8-groups; entry e = kh*128 + j*32 + col holds
// W[k8 = base + kh*4 + j][colbase + col] (8 f16). Lane owns a column ->
// register accumulate, ONE shfl_xor(32) per block (no per-subtile reduce).
// Per wave per step 192 sub-tiles: CKV 6blk*4, per layer [QKV 3*4 | WO 4 |
// CAQ 4 | CAO 4 | FF1 4*4 | FF2 1*16].
#define SUBT_W   192
#define TOTAL_ENT (8 * SUBT_W * 256)

__device__ __forceinline__ float wave_sum64(float v) {
#pragma unroll
  for (int off = 32; off > 0; off >>= 1) v += __shfl_xor(v, off, 64);
  return v;
}
__device__ __forceinline__ float wave_max64(float v) {
#pragma unroll
  for (int off = 32; off > 0; off >>= 1) v = fmaxf(v, __shfl_xor(v, off, 64));
  return v;
}
__device__ __forceinline__ float gelu_f(float x) {
  return 0.5f * x * (1.0f + erff(x * 0.7071067811865476f));
}
__device__ __forceinline__ uint16_t f2bf(float v) {
  uint32_t b = __float_as_uint(v);
  return (uint16_t)((b + 0x7fffu + ((b >> 16) & 1u)) >> 16);
}
__device__ __forceinline__ float bl16(uint32_t w) { return __uint_as_float(w << 16); }
__device__ __forceinline__ float bh16(uint32_t w) { return __uint_as_float(w & 0xffff0000u); }
__device__ __forceinline__ uint16_t f2h(float v) {
  _Float16 h = (_Float16)v;
  return __builtin_bit_cast(uint16_t, h);
}
__device__ __forceinline__ uint32_t pk2(float lo_, float hi_) {
  return ((uint32_t)f2h(hi_) << 16) | (uint32_t)f2h(lo_);
}
__device__ __forceinline__ float fdot2a(uint32_t a, uint32_t b, float acc) {
  asm("v_dot2_f32_f16 %0, %1, %2, %0" : "+v"(acc) : "v"(a), "v"(b));
  return acc;
}

#define SYNC() do { __builtin_amdgcn_sched_barrier(0); \
  asm volatile("s_waitcnt lgkmcnt(0)" ::: "memory"); \
  __builtin_amdgcn_s_barrier(); \
  __builtin_amdgcn_sched_barrier(0); } while (0)
#define VMWAIT8() do { __builtin_amdgcn_sched_barrier(0); \
  asm volatile("s_waitcnt vmcnt(8)" ::: "memory"); \
  __builtin_amdgcn_sched_barrier(0); } while (0)

__device__ __forceinline__ void gld_lds16(const uint4* g, uint4* l) {
  __builtin_amdgcn_global_load_lds(
      (const __attribute__((address_space(1))) void*)g,
      (__attribute__((address_space(3))) void*)l, 16, 0, 0);
}

__device__ __forceinline__ float ln_norm_256(float x, float g, float b, float* sbuf, int tid) {
  float s = wave_sum64(x);
  if ((tid & 63) == 0) sbuf[tid >> 6] = s;
  __syncthreads();
  float mean = (sbuf[0] + sbuf[1] + sbuf[2] + sbuf[3]) * (1.0f / 256.0f);
  __syncthreads();
  float d = x - mean;
  float vs = wave_sum64(d * d);
  if ((tid & 63) == 0) sbuf[tid >> 6] = vs;
  __syncthreads();
  float var = (sbuf[0] + sbuf[1] + sbuf[2] + sbuf[3]) * (1.0f / 256.0f);
  return d * rsqrtf(var + 1e-5f) * g + b;
}

// ======================= MFMA bf16 prefill GEMM =======================
#define LDK 72

__global__ __launch_bounds__(256) void k_gemm_mf(
    const float* __restrict__ A, const float* __restrict__ W,
    const float* __restrict__ bias, const float* __restrict__ Rres,
    float* __restrict__ C, int M, int N, int K, int act, int outmode,
    float* __restrict__ qout, __hip_bfloat16* __restrict__ kc,
    __hip_bfloat16* __restrict__ vc, __hip_bfloat16* __restrict__ c6,
    int rows_per_b, int pos_base)
{
  typedef __attribute__((ext_vector_type(8))) short bf8;
  typedef __attribute__((ext_vector_type(4))) float f4;
  __shared__ short Al[2][128 * LDK];
  __shared__ short Bl[2][64 * LDK];
  const int tid = threadIdx.x;
  const int wv = tid >> 6, lane = tid & 63;
  const int bm0 = blockIdx.y * 128, bn0 = blockIdx.x * 64;
  const int nkt = K >> 6;
  const int ar = tid >> 1, ah = (tid & 1) << 5;
  const int br = tid >> 2, bq = (tid & 3) << 4;

  f4 acc[2][4];
#pragma unroll
  for (int i = 0; i < 2; i++)
#pragma unroll
    for (int j = 0; j < 4; j++) acc[i][j] = (f4)0.f;

  auto stage = [&](int buf, int kt) {
    const int k0 = kt << 6;
    const float* ap = A + (size_t)(bm0 + ar) * K + k0 + ah;
    float4 av[8];
#pragma unroll
    for (int u = 0; u < 8; u++) av[u] = *(const float4*)(ap + 4 * u);
    const float* wp = W + (size_t)(bn0 + br) * K + k0 + bq;
    float4 wv4[4];
#pragma unroll
    for (int u = 0; u < 4; u++) wv4[u] = *(const float4*)(wp + 4 * u);
    short* ad = &Al[buf][ar * LDK + ah];
#pragma unroll
    for (int u = 0; u < 8; u++) {
      short4 sv = {(short)f2bf(av[u].x), (short)f2bf(av[u].y),
                   (short)f2bf(av[u].z), (short)f2bf(av[u].w)};
      *(short4*)(ad + 4 * u) = sv;
    }
    short* bd = &Bl[buf][br * LDK + bq];
#pragma unroll
    for (int u = 0; u < 4; u++) {
      short4 sv = {(short)f2bf(wv4[u].x), (short)f2bf(wv4[u].y),
                   (short)f2bf(wv4[u].z), (short)f2bf(wv4[u].w)};
      *(short4*)(bd + 4 * u) = sv;
    }
  };

  auto comp = [&](int buf) {
    const int am = wv * 32 + (lane & 15);
    const int bn = lane & 15;
    const int kb = (lane >> 4) * 8;
#pragma unroll
    for (int kk = 0; kk < 2; kk++) {
      const int ko = kk * 32 + kb;
      bf8 a0 = *(const bf8*)&Al[buf][am * LDK + ko];
      bf8 a1 = *(const bf8*)&Al[buf][(am + 16) * LDK + ko];
      bf8 b0 = *(const bf8*)&Bl[buf][bn * LDK + ko];
      bf8 b1 = *(const bf8*)&Bl[buf][(bn + 16) * LDK + ko];
      bf8 b2 = *(const bf8*)&Bl[buf][(bn + 32) * LDK + ko];
      bf8 b3 = *(const bf8*)&Bl[buf][(bn + 48) * LDK + ko];
      acc[0][0] = __builtin_amdgcn_mfma_f32_16x16x32_bf16(a0, b0, acc[0][0], 0, 0, 0);
      acc[0][1] = __builtin_amdgcn_mfma_f32_16x16x32_bf16(a0, b1, acc[0][1], 0, 0, 0);
      acc[0][2] = __builtin_amdgcn_mfma_f32_16x16x32_bf16(a0, b2, acc[0][2], 0, 0, 0);
      acc[0][3] = __builtin_amdgcn_mfma_f32_16x16x32_bf16(a0, b3, acc[0][3], 0, 0, 0);
      acc[1][0] = __builtin_amdgcn_mfma_f32_16x16x32_bf16(a1, b0, acc[1][0], 0, 0, 0);
      acc[1][1] = __builtin_amdgcn_mfma_f32_16x16x32_bf16(a1, b1, acc[1][1], 0, 0, 0);
      acc[1][2] = __builtin_amdgcn_mfma_f32_16x16x32_bf16(a1, b2, acc[1][2], 0, 0, 0);
      acc[1][3] = __builtin_amdgcn_mfma_f32_16x16x32_bf16(a1, b3, acc[1][3], 0, 0, 0);
    }
  };

  stage(0, 0);
  __syncthreads();
  for (int kt = 0; kt < nkt; kt++) {
    if (kt + 1 < nkt) stage((kt & 1) ^ 1, kt + 1);
    comp(kt & 1);
    __syncthreads();
  }

  const int n0 = bn0 + (lane & 15);
  const int r0 = bm0 + wv * 32 + (lane >> 4) * 4;
#pragma unroll
  for (int i = 0; i < 2; i++) {
#pragma unroll
    for (int r = 0; r < 4; r++) {
      const int row = r0 + i * 16 + r;
      const int b = row / rows_per_b;
      const int t = pos_base + row % rows_per_b;
#pragma unroll
      for (int j = 0; j < 4; j++) {
        const int n = n0 + j * 16;
        float v = acc[i][j][r] + bias[n];
        if (Rres) v += Rres[(size_t)row * N + n];
        if (act) v = gelu_f(v);
        if (outmode == 0) {
          C[(size_t)row * N + n] = v;
        } else if (outmode == 1) {
          if (n < 256) qout[(size_t)row * DMODEL + n] = v;
          else if (n < 512) kc[((size_t)b * S_TOT + t) * DMODEL + (n - 256)] = __float2bfloat16(v);
          else vc[((size_t)b * S_TOT + t) * DMODEL + (n - 512)] = __float2bfloat16(v);
        } else {
          const int j6 = n >> 8;
          c6[(size_t)j6 * ((size_t)BATCH * S_TOT * DMODEL) +
             ((size_t)b * S_TOT + t) * DMODEL + (n & 255)] = __float2bfloat16(v);
        }
      }
    }
  }
}

// ======================= other prefill kernels (unchanged) =================
__global__ __launch_bounds__(64) void k_attn(
    const float* __restrict__ qbuf, const __hip_bfloat16* __restrict__ kc,
    const __hip_bfloat16* __restrict__ vc, float* __restrict__ outb,
    int rows_per_b, int pos_base)
{
  __shared__ float qs[DHEAD];
  __shared__ float ss[S_TOT];
  const int bid = blockIdx.x;
  const int h = bid & (HEADS - 1);
  const int row = bid >> 3;
  const int b = row / rows_per_b;
  const int t = pos_base + row % rows_per_b;
  const int nk = t + 1;
  const int lane = threadIdx.x;
  if (lane < DHEAD) qs[lane] = qbuf[(size_t)row * DMODEL + h * DHEAD + lane];
  __syncthreads();
  float mx = -1e30f;
  for (int k0 = lane; k0 < nk; k0 += 64) {
    const __hip_bfloat16* kp = kc + ((size_t)b * S_TOT + k0) * DMODEL + h * DHEAD;
    float s = 0.f;
#pragma unroll
    for (int i = 0; i < DHEAD; i++) s += qs[i] * __bfloat162float(kp[i]);
    s *= 0.17677669529663687f;
    ss[k0] = s;
    mx = fmaxf(mx, s);
  }
  mx = wave_max64(mx);
  float sum = 0.f;
  for (int k0 = lane; k0 < nk; k0 += 64) {
    float e = expf(ss[k0] - mx);
    ss[k0] = e;
    sum += e;
  }
  sum = wave_sum64(sum);
  __syncthreads();
  const float inv = 1.0f / sum;
  if (lane < DHEAD) {
    float o = 0.f;
    for (int k0 = 0; k0 < nk; k0++)
      o += ss[k0] * __bfloat162float(vc[((size_t)b * S_TOT + k0) * DMODEL + h * DHEAD + lane]);
    outb[(size_t)row * DMODEL + h * DHEAD + lane] = o * inv;
  }
}

__global__ __launch_bounds__(256) void k_ln(
    const float* __restrict__ Z, const float* __restrict__ g,
    const float* __restrict__ b, float* __restrict__ out)
{
  __shared__ float sbuf[4];
  const int row = blockIdx.x, tid = threadIdx.x;
  float x = Z[(size_t)row * DMODEL + tid];
  out[(size_t)row * DMODEL + tid] = ln_norm_256(x, g[tid], b[tid], sbuf, tid);
}

__global__ __launch_bounds__(256) void k_embed(
    const float* __restrict__ past, const float* __restrict__ in_W,
    const float* __restrict__ in_b, const float* __restrict__ pos_emb,
    const float* __restrict__ ln_w, const float* __restrict__ ln_b,
    float* __restrict__ Aout)
{
  __shared__ float sbuf[4];
  const int rowid = blockIdx.x;
  const int b = rowid / PAST_N, t = rowid % PAST_N;
  const int tid = threadIdx.x;
  float dx = 0.f, dy = 0.f;
  if (t > 0) {
    dx = past[((size_t)b * PAST_N + t) * 2 + 0] - past[((size_t)b * PAST_N + t - 1) * 2 + 0];
    dy = past[((size_t)b * PAST_N + t) * 2 + 1] - past[((size_t)b * PAST_N + t - 1) * 2 + 1];
  }
  float v = in_W[tid * 2 + 0] * dx + in_W[tid * 2 + 1] * dy + in_b[tid] +
            pos_emb[(size_t)t * DMODEL + tid];
  Aout[(size_t)rowid * DMODEL + tid] = ln_norm_256(v, ln_w[tid], ln_b[tid], sbuf, tid);
}

__global__ __launch_bounds__(256) void k_prepack(
    const float* __restrict__ caW, const float* __restrict__ cab,
    float* __restrict__ Wckv, float* __restrict__ bckv)
{
  const int n = blockIdx.x, tid = threadIdx.x;
  const int j = n >> 8, dcol = n & 255;
  const int l = j >> 1, kv = j & 1;
  const int srow = l * 768 + 256 + kv * 256 + dcol;
  Wckv[(size_t)n * 256 + tid] = caW[(size_t)srow * 256 + tid];
  if (tid == 0) bckv[n] = cab[l * 768 + 256 + kv * 256 + dcol];
}

__global__ __launch_bounds__(64) void k_readout(
    const float* __restrict__ X, const float* __restrict__ out_W,
    const float* __restrict__ out_b, const float* __restrict__ past,
    float* __restrict__ cur, float* __restrict__ ndb, float* __restrict__ out,
    int rows_per_b, int s, int init)
{
  const int b = blockIdx.x, lane = threadIdx.x;
  const int row = b * rows_per_b + rows_per_b - 1;
  float p0 = 0.f, p1 = 0.f;
  for (int d = lane; d < DMODEL; d += 64) {
    const float xv = X[(size_t)row * DMODEL + d];
    p0 += xv * out_W[d];
    p1 += xv * out_W[DMODEL + d];
  }
  p0 = wave_sum64(p0);
  p1 = wave_sum64(p1);
  if (lane == 0) {
    const float nd0 = p0 + out_b[0];
    const float nd1 = p1 + out_b[1];
    float c0, c1;
    if (init) {
      c0 = past[((size_t)b * PAST_N + PAST_N - 1) * 2 + 0];
      c1 = past[((size_t)b * PAST_N + PAST_N - 1) * 2 + 1];
    } else {
      c0 = cur[b * 2 + 0];
      c1 = cur[b * 2 + 1];
    }
    c0 += nd0; c1 += nd1;
    cur[b * 2 + 0] = c0; cur[b * 2 + 1] = c1;
    ndb[b * 2 + 0] = nd0; ndb[b * 2 + 1] = nd1;
    out[((size_t)b * FUT_N + s) * 2 + 0] = c0;
    out[((size_t)b * FUT_N + s) * 2 + 1] = c1;
  }
}

// ======================= decode stream pack (col-per-lane layout) ==========
__global__ __launch_bounds__(256) void k_pack_stream(
    const float* __restrict__ sa_Wqkv, const float* __restrict__ sa_Wo,
    const float* __restrict__ ca_Wqkv, const float* __restrict__ ca_Wo,
    const float* __restrict__ ff1_W, const float* __restrict__ ff2_W,
    uint4* __restrict__ Wd)
{
  const unsigned gidx = blockIdx.x * 256 + threadIdx.x;
  if (gidx >= TOTAL_ENT) return;
  const unsigned w = gidx / (SUBT_W * 256);
  const unsigned r = gidx % (SUBT_W * 256);
  const unsigned n = r >> 8, e = r & 255u;
  const int kh = e >> 7, j = (e >> 5) & 3, c = e & 31;
  const int k8l = kh * 4 + j;   // k8 within sub-tile (0..7)
  const float* src;
  if (n < 24) {
    // CKV: 6 blocks x 4 subtiles; col = w*192 + blk*32 + c; k8 = st*8 + k8l
    const int blk = n >> 2, st = n & 3;
    const int col = (int)(w * 192 + blk * 32 + c);
    const int k8 = st * 8 + k8l;
    const int j6 = col >> 8, dcol = col & 255, lq = j6 >> 1, kv = j6 & 1;
    src = ca_Wqkv + (size_t)lq * 196608 + (size_t)(256 + kv * 256 + dcol) * 256 + 8 * k8;
  } else {
    const unsigned m = n - 24;
    const int l = m / 56, p = m % 56;
    if (p < 12) {          // QKV: 3 blocks x 4
      const int blk = p >> 2, st = p & 3;
      const int col = w * 96 + blk * 32 + c;
      const int k8 = st * 8 + k8l;
      src = sa_Wqkv + (size_t)l * 196608 + (size_t)col * 256 + 8 * k8;
    } else if (p < 16) {   // WO: 1 block x 4
      const int st = p - 12;
      const int col = w * 32 + c;
      const int k8 = st * 8 + k8l;
      src = sa_Wo + (size_t)l * 65536 + (size_t)col * 256 + 8 * k8;
    } else if (p < 20) {   // CAQ
      const int st = p - 16;
      const int col = w * 32 + c;
      const int k8 = st * 8 + k8l;
      src = ca_Wqkv + (size_t)l * 196608 + (size_t)col * 256 + 8 * k8;
    } else if (p < 24) {   // CAO
      const int st = p - 20;
      const int col = w * 32 + c;
      const int k8 = st * 8 + k8l;
      src = ca_Wo + (size_t)l * 65536 + (size_t)col * 256 + 8 * k8;
    } else if (p < 40) {   // FF1: 4 blocks x 4
      const int pp = p - 24;
      const int blk = pp >> 2, st = pp & 3;
      const int col = w * 128 + blk * 32 + c;
      const int k8 = st * 8 + k8l;
      src = ff1_W + (size_t)l * 262144 + (size_t)col * 256 + 8 * k8;
    } else {               // FF2: 1 block x 16 (K=1024)
      const int st = p - 40;
      const int col = w * 32 + c;
      const int k8 = st * 8 + k8l;
      src = ff2_W + (size_t)l * 262144 + (size_t)col * 1024 + 8 * k8;
    }
  }
  uint4 u;
  u.x = ((uint32_t)f2h(src[1]) << 16) | (uint32_t)f2h(src[0]);
  u.y = ((uint32_t)f2h(src[3]) << 16) | (uint32_t)f2h(src[2]);
  u.z = ((uint32_t)f2h(src[5]) << 16) | (uint32_t)f2h(src[4]);
  u.w = ((uint32_t)f2h(src[7]) << 16) | (uint32_t)f2h(src[6]);
  Wd[gidx] = u;
}

// ======================= fused 19-step decode =======================
__global__ __launch_bounds__(NT) void k_decode(
    const uint4* __restrict__ Wd, const float* __restrict__ bckv,
    const float* __restrict__ in_W, const float* __restrict__ in_b,
    const float* __restrict__ pos_emb,
    const float* __restrict__ ln0_w, const float* __restrict__ ln0_b,
    const float* __restrict__ sa_bqkv, const float* __restrict__ sa_bo,
    const float* __restrict__ ca_bqkv, const float* __restrict__ ca_bo,
    const float* __restrict__ ff1_b, const float* __restrict__ ff2_b,
    const float* __restrict__ ln1_w, const float* __restrict__ ln1_b,
    const float* __restrict__ ln2_w, const float* __restrict__ ln2_b,
    const float* __restrict__ ln3_w, const float* __restrict__ ln3_b,
    const float* __restrict__ out_W, const float* __restrict__ out_b,
    __hip_bfloat16* __restrict__ Ksa, __hip_bfloat16* __restrict__ Vsa,
    __hip_bfloat16* __restrict__ C6,
    const float* __restrict__ ndb, const float* __restrict__ cur,
    float* __restrict__ out)
{
  const int b = blockIdx.x;
  const int tid = threadIdx.x;
  const int wv = tid >> 6, lane = tid & 63;
  const int sv = (wv + b) & 7;   // stream slot: desync same-XCD CUs
  const size_t slab = (size_t)BATCH * S_TOT * DMODEL;

  __shared__ __align__(16) uint4 ring[8 * 4 * 256];   // 128 KB
  __shared__ __align__(16) float x[256];
  __shared__ __align__(16) float xt[256];
  __shared__ __align__(16) float q[256];
  __shared__ __align__(16) float hbuf[1024];
  __shared__ __align__(16) float pred[256];
  __shared__ __align__(16) float kn[256], vn[256];
  __shared__ __align__(16) float ckvn[1536];
  __shared__ __align__(16) uint32_t xh[128], xth[128], atth[128], hh[512];
  __shared__ float ss[8][72];
  __shared__ float sb[8], sb2[8];
  __shared__ float ndc[4];

  const bool lo = tid < 256;
  const float c_bk0 = bckv[tid], c_bk1 = bckv[tid + 512], c_bk2 = bckv[tid + 1024];
  float c_inW0 = 0.f, c_inW1 = 0.f, c_inb = 0.f, c_l0w = 0.f, c_l0b = 0.f;
  if (lo) {
    c_inW0 = in_W[2 * tid]; c_inW1 = in_W[2 * tid + 1]; c_inb = in_b[tid];
    c_l0w = ln0_w[tid];     c_l0b = ln0_b[tid];
  }
  float bq0[LAYERS], bq1[LAYERS], bso[LAYERS], bcq[LAYERS], bco[LAYERS];
  float bf10[LAYERS], bf11[LAYERS], bf2[LAYERS];
  float w1[LAYERS], bb1[LAYERS], w2[LAYERS], bb2[LAYERS], w3[LAYERS], bb3[LAYERS];
#pragma unroll
  for (int l = 0; l < LAYERS; l++) {
    bq0[l] = sa_bqkv[l * 768 + tid];
    bq1[l] = lo ? sa_bqkv[l * 768 + 512 + tid] : 0.f;
    bso[l] = lo ? sa_bo[l * 256 + tid] : 0.f;
    bcq[l] = lo ? ca_bqkv[l * 768 + tid] : 0.f;
    bco[l] = lo ? ca_bo[l * 256 + tid] : 0.f;
    bf10[l] = ff1_b[l * 1024 + tid];
    bf11[l] = ff1_b[l * 1024 + 512 + tid];
    bf2[l] = lo ? ff2_b[l * 256 + tid] : 0.f;
    w1[l] = lo ? ln1_w[l * 256 + tid] : 0.f;  bb1[l] = lo ? ln1_b[l * 256 + tid] : 0.f;
    w2[l] = lo ? ln2_w[l * 256 + tid] : 0.f;  bb2[l] = lo ? ln2_b[l * 256 + tid] : 0.f;
    w3[l] = lo ? ln3_w[l * 256 + tid] : 0.f;  bb3[l] = lo ? ln3_b[l * 256 + tid] : 0.f;
  }
  float c_ow[4] = {0.f, 0.f, 0.f, 0.f};
  float c_ob = 0.f;
  if (tid < 128) {
    const int d0 = tid >> 6, ll = tid & 63;
#pragma unroll
    for (int j = 0; j < 4; j++) c_ow[j] = out_W[d0 * 256 + ll + 64 * j];
    c_ob = out_b[d0];
  }
  if (tid == 0) {
    ndc[0] = ndb[2 * b];     ndc[1] = ndb[2 * b + 1];
    ndc[2] = cur[2 * b];     ndc[3] = cur[2 * b + 1];
  }
  asm volatile("s_waitcnt vmcnt(0)" ::: "memory");

  auto issue = [&](unsigned g) {
    const unsigned sidx = g % (unsigned)SUBT_W;
    const unsigned slot = g & 3u;
    const uint4* src = Wd + (((size_t)sv * SUBT_W + sidx) << 8) + lane;
    uint4* dst = &ring[(((unsigned)wv << 2) | slot) * 256u + (unsigned)lane];
#pragma unroll
    for (int j = 0; j < 4; j++) gld_lds16(src + (j << 6), dst + (j << 6));
  };

  // block GEMV: nblk column-blocks of 32, nst sub-tiles each (8 k8 per
  // sub-tile). Lane owns col (l&31); halves split K; ONE shfl per block.
  auto gemvB = [&](unsigned& g, int nblk, int nst, const uint4* xp, auto&& emit) {
    const int kh = lane >> 5, c = lane & 31;
    for (int bi = 0; bi < nblk; bi++) {
      float acc = 0.f;
      for (int st = 0; st < nst; st++) {
        VMWAIT8();
        issue(g + 3);
        const uint4* S = &ring[(((unsigned)wv << 2) | (g & 3u)) * 256u] + kh * 128 + c;
        const uint4 W0 = S[0], W1 = S[32], W2 = S[64], W3 = S[96];
        const int kb = st * 8 + kh * 4;
        const uint4 X0 = xp[kb], X1 = xp[kb + 1], X2 = xp[kb + 2], X3 = xp[kb + 3];
        acc = fdot2a(W0.x, X0.x, acc); acc = fdot2a(W0.y, X0.y, acc);
        acc = fdot2a(W0.z, X0.z, acc); acc = fdot2a(W0.w, X0.w, acc);
        acc = fdot2a(W1.x, X1.x, acc); acc = fdot2a(W1.y, X1.y, acc);
        acc = fdot2a(W1.z, X1.z, acc); acc = fdot2a(W1.w, X1.w, acc);
        acc = fdot2a(W2.x, X2.x, acc); acc = fdot2a(W2.y, X2.y, acc);
        acc = fdot2a(W2.z, X2.z, acc); acc = fdot2a(W2.w, X2.w, acc);
        acc = fdot2a(W3.x, X3.x, acc); acc = fdot2a(W3.y, X3.y, acc);
        acc = fdot2a(W3.z, X3.z, acc); acc = fdot2a(W3.w, X3.w, acc);
        g++;
      }
      acc += __shfl_xor(acc, 32, 64);
      if (lane < 32) emit(bi * 32 + c, acc);
    }
  };

  auto ln_store = [&](float v, float gw_, float gb_, float* dst, uint32_t* dsth) {
    float vv = lo ? v : 0.f;
    float s  = wave_sum64(vv);
    float s2 = wave_sum64(vv * vv);
    if ((tid & 63) == 0) { sb[tid >> 6] = s; sb2[tid >> 6] = s2; }
    SYNC();
    float mean = (sb[0] + sb[1] + sb[2] + sb[3]) * (1.0f / 256.0f);
    float ex2  = (sb2[0] + sb2[1] + sb2[2] + sb2[3]) * (1.0f / 256.0f);
    float var = ex2 - mean * mean;
    float vn_ = (vv - mean) * rsqrtf(var + 1e-5f) * gw_ + gb_;
    float vo = __shfl_xor(vn_, 1, 64);
    if (lo) {
      dst[tid] = vn_;
      if (!(tid & 1)) dsth[tid >> 1] = pk2(vn_, vo);
    }
    SYNC();
  };

  auto attn8 = [&](const __hip_bfloat16* Kc, const __hip_bfloat16* Vc,
                   const float* knw, const float* vnw, int pos) {
    const int h = wv;
    const float* qh = q + h * 32;
    float mx = -1e30f;
    for (int k0 = lane; k0 <= pos; k0 += 64) {
      float s = 0.f;
      if (k0 == pos) {
        const float* kp = knw + h * 32;
#pragma unroll
        for (int i = 0; i < 32; i++) s += qh[i] * kp[i];
      } else {
        const uint32_t* kp = (const uint32_t*)(Kc + ((size_t)b * S_TOT + k0) * DMODEL + h * 32);
#pragma unroll
        for (int i = 0; i < 16; i++) {
          uint32_t w = kp[i];
          s += bl16(w) * qh[2 * i];
          s += bh16(w) * qh[2 * i + 1];
        }
      }
      s *= 0.17677669529663687f;
      ss[h][k0] = s;
      mx = fmaxf(mx, s);
    }
    mx = wave_max64(mx);
    float sum = 0.f;
    for (int k0 = lane; k0 <= pos; k0 += 64) {
      float e = __expf(ss[h][k0] - mx);
      ss[h][k0] = e;
      sum += e;
    }
    sum = wave_sum64(sum);
    const float inv = 1.0f / sum;
    const int kpar = lane >> 4, d2 = lane & 15;
    const uint32_t* vbase = (const uint32_t*)(Vc + (size_t)b * S_TOT * DMODEL + h * 32) + d2;
    float oA = 0.f, oB = 0.f;
    for (int k0 = kpar; k0 < pos; k0 += 4) {
      const uint32_t w = vbase[(size_t)k0 * (DMODEL / 2)];
      const float p = ss[h][k0];
      oA += p * bl16(w);
      oB += p * bh16(w);
    }
    oA += __shfl_xor(oA, 16, 64); oA += __shfl_xor(oA, 32, 64);
    oB += __shfl_xor(oB, 16, 64); oB += __shfl_xor(oB, 32, 64);
    if (kpar == 0) {
      const float p = ss[h][pos];
      oA += p * vnw[h * 32 + 2 * d2];
      oB += p * vnw[h * 32 + 2 * d2 + 1];
      atth[h * 16 + d2] = pk2(oA * inv, oB * inv);
    }
  };

  unsigned g = 0;
  issue(0); issue(1); issue(2);

  for (int s = 1; s < FUT_N; s++) {
    const int pos = PAST_N - 1 + s;

    float xe = 0.f;
    if (lo) {
      xe = c_inW0 * ndc[0] + c_inW1 * ndc[1] + c_inb + pos_emb[(size_t)pos * DMODEL + tid];
    }
    ln_store(xe, c_l0w, c_l0b, xt, xth);
    if (lo) x[tid] = xt[tid];
    if (tid < 128) xh[tid] = xth[tid];

    // CKV: 6 blocks x 4, input xth; cols sv*192 + ...
    gemvB(g, 6, 4, (const uint4*)xth, [&](int cl, float a) { ckvn[sv * 192 + cl] = a; });
    SYNC();
    {
      float v0 = ckvn[tid] + c_bk0;
      float v1 = ckvn[tid + 512] + c_bk1;
      float v2 = ckvn[tid + 1024] + c_bk2;
      ckvn[tid] = v0; ckvn[tid + 512] = v1; ckvn[tid + 1024] = v2;
      int n = tid;
      C6[(size_t)(n >> 8) * slab + ((size_t)b * S_TOT + pos) * DMODEL + (n & 255)] = __float2bfloat16(v0);
      n = tid + 512;
      C6[(size_t)(n >> 8) * slab + ((size_t)b * S_TOT + pos) * DMODEL + (n & 255)] = __float2bfloat16(v1);
      n = tid + 1024;
      C6[(size_t)(n >> 8) * slab + ((size_t)b * S_TOT + pos) * DMODEL + (n & 255)] = __float2bfloat16(v2);
      SYNC();
    }

#pragma unroll
    for (int l = 0; l < LAYERS; l++) {
      // a. QKV: 3 blocks x 4, input xh; cols sv*96 + ...
      gemvB(g, 3, 4, (const uint4*)xh, [&](int cl, float a) {
        const int col = sv * 96 + cl;
        if (col < 256) q[col] = a;
        else if (col < 512) kn[col - 256] = a;
        else vn[col - 512] = a;
      });
      SYNC();
      {
        if (tid < 256) q[tid] += bq0[l];
        else {
          float v2 = kn[tid - 256] + bq0[l];
          kn[tid - 256] = v2;
          Ksa[(size_t)l * slab + ((size_t)b * S_TOT + pos) * DMODEL + (tid - 256)] = __float2bfloat16(v2);
        }
        if (lo) {
          float v2 = vn[tid] + bq1[l];
          vn[tid] = v2;
          Vsa[(size_t)l * slab + ((size_t)b * S_TOT + pos) * DMODEL + tid] = __float2bfloat16(v2);
        }
        SYNC();
      }
      // b. SA attention
      attn8(Ksa + (size_t)l * slab, Vsa + (size_t)l * slab, kn, vn, pos);
      SYNC();
      // c. WO: 1 block x 4, input atth
      gemvB(g, 1, 4, (const uint4*)atth, [&](int cl, float a) { pred[sv * 32 + cl] = a; });
      SYNC();
      ln_store(lo ? (x[tid] + pred[tid] + bso[l]) : 0.f, w1[l], bb1[l], x, xh);
      // d. CAQ: 1 block x 4, input xh
      gemvB(g, 1, 4, (const uint4*)xh, [&](int cl, float a) { pred[sv * 32 + cl] = a; });
      SYNC();
      if (lo) q[tid] = pred[tid] + bcq[l];
      SYNC();
      // e. CA attention
      attn8(C6 + (size_t)(2 * l) * slab, C6 + (size_t)(2 * l + 1) * slab,
            ckvn + l * 512, ckvn + l * 512 + 256, pos);
      SYNC();
      // f. CAO: 1 block x 4, input atth
      gemvB(g, 1, 4, (const uint4*)atth, [&](int cl, float a) { pred[sv * 32 + cl] = a; });
      SYNC();
      ln_store(lo ? (x[tid] + pred[tid] + bco[l]) : 0.f, w2[l], bb2[l], x, xh);
      // g. FF1: 4 blocks x 4, input xh; cols sv*128 + ...
      gemvB(g, 4, 4, (const uint4*)xh, [&](int cl, float a) { hbuf[sv * 128 + cl] = a; });
      SYNC();
      {
        float g0 = gelu_f(hbuf[tid] + bf10[l]);
        float g1 = gelu_f(hbuf[tid + 512] + bf11[l]);
        float o0 = __shfl_xor(g0, 1, 64), o1 = __shfl_xor(g1, 1, 64);
        if (!(tid & 1)) {
          hh[tid >> 1] = pk2(g0, o0);
          hh[(tid + 512) >> 1] = pk2(g1, o1);
        }
        SYNC();
      }
      // h. FF2: 1 block x 16 (K=1024), input hh
      gemvB(g, 1, 16, (const uint4*)hh, [&](int cl, float a) { pred[sv * 32 + cl] = a; });
      SYNC();
      ln_store(lo ? (x[tid] + pred[tid] + bf2[l]) : 0.f, w3[l], bb3[l], x, xh);
    }

    // readout
    {
      const int ll = tid & 63;
      if (tid < 128) {
        const int d0 = tid >> 6;
        float p = 0.f;
#pragma unroll
        for (int j = 0; j < 4; j++) p += x[ll + 64 * j] * c_ow[j];
        p = wave_sum64(p);
        if (ll == 0) {
          const float nd = p + c_ob;
          ndc[d0] = nd;
          const float c = ndc[2 + d0] + nd;
          ndc[2 + d0] = c;
          out[((size_t)b * FUT_N + s) * 2 + d0] = c;
        }
      }
      SYNC();
    }
  }
  asm volatile("s_waitcnt vmcnt(0)" ::: "memory");
}

// ======================= host launch =======================
extern "C" void kernel_launch(void* const* d_in, const int* in_sizes, int n_in,
                              void* d_out, int out_size, void* d_ws, size_t ws_size,
                              hipStream_t stream)
{
  const float* past    = (const float*)d_in[0];
  const float* in_W    = (const float*)d_in[1];
  const float* in_b    = (const float*)d_in[2];
  const float* pos_emb = (const float*)d_in[3];
  const float* ln0_w   = (const float*)d_in[4];
  const float* ln0_b   = (const float*)d_in[5];
  const float* sa_Wqkv = (const float*)d_in[6];
  const float* sa_bqkv = (const float*)d_in[7];
  const float* sa_Wo   = (const float*)d_in[8];
  const float* sa_bo   = (const float*)d_in[9];
  const float* ca_Wqkv = (const float*)d_in[10];
  const float* ca_bqkv = (const float*)d_in[11];
  const float* ca_Wo   = (const float*)d_in[12];
  const float* ca_bo   = (const float*)d_in[13];
  const float* ff1_W   = (const float*)d_in[14];
  const float* ff1_b   = (const float*)d_in[15];
  const float* ff2_W   = (const float*)d_in[16];
  const float* ff2_b   = (const float*)d_in[17];
  const float* ln1_w   = (const float*)d_in[18];
  const float* ln1_b   = (const float*)d_in[19];
  const float* ln2_w   = (const float*)d_in[20];
  const float* ln2_b   = (const float*)d_in[21];
  const float* ln3_w   = (const float*)d_in[22];
  const float* ln3_b   = (const float*)d_in[23];
  const float* out_W   = (const float*)d_in[24];
  const float* out_b   = (const float*)d_in[25];
  float* out = (float*)d_out;

  const size_t Mpre = (size_t)BATCH * PAST_N;              // 6400
  const size_t slab = (size_t)BATCH * S_TOT * DMODEL;      // 2,293,760

  float* ws_f = (float*)d_ws;
  float* A    = ws_f;
  float* Bb   = A + Mpre * DMODEL;
  float* qb   = Bb + Mpre * DMODEL;
  float* at   = qb + Mpre * DMODEL;
  float* hb   = at + Mpre * DMODEL;
  float* Wckv = hb + Mpre * FFD;
  float* bckv = Wckv + (size_t)1536 * 256;
  float* ndb  = bckv + 1536;
  float* cur  = ndb + 256;
  __hip_bfloat16* Ksa = (__hip_bfloat16*)(cur + 256);
  __hip_bfloat16* Vsa = Ksa + 3 * slab;
  __hip_bfloat16* C6  = Vsa + 3 * slab;
  uint4* Wd = (uint4*)A;  // decode stream aliases A (dead after prefill)

  const size_t need = ((size_t)(C6 + 6 * slab) - (size_t)d_ws);
  if (ws_size < need) return;

  auto layer = [&](int l, int M, int rpb, int pbase) {
    const float* Wqkv = sa_Wqkv + (size_t)l * 768 * 256;
    __hip_bfloat16* kcl = Ksa + (size_t)l * slab;
    __hip_bfloat16* vcl = Vsa + (size_t)l * slab;
    k_gemm_mf<<<dim3(768 / 64, M / 128), 256, 0, stream>>>(
        A, Wqkv, sa_bqkv + l * 768, nullptr, nullptr, M, 768, 256, 0, 1,
        qb, kcl, vcl, nullptr, rpb, pbase);
    k_attn<<<M * HEADS, 64, 0, stream>>>(qb, kcl, vcl, at, rpb, pbase);
    k_gemm_mf<<<dim3(256 / 64, M / 128), 256, 0, stream>>>(
        at, sa_Wo + (size_t)l * 65536, sa_bo + l * 256, A, Bb, M, 256, 256, 0, 0,
        nullptr, nullptr, nullptr, nullptr, 1, 0);
    k_ln<<<M, 256, 0, stream>>>(Bb, ln1_w + l * 256, ln1_b + l * 256, A);
    k_gemm_mf<<<dim3(256 / 64, M / 128), 256, 0, stream>>>(
        A, ca_Wqkv + (size_t)l * 768 * 256, ca_bqkv + l * 768, nullptr, qb,
        M, 256, 256, 0, 0, nullptr, nullptr, nullptr, nullptr, 1, 0);
    k_attn<<<M * HEADS, 64, 0, stream>>>(
        qb, C6 + (size_t)(2 * l) * slab, C6 + (size_t)(2 * l + 1) * slab, at, rpb, pbase);
    k_gemm_mf<<<dim3(256 / 64, M / 128), 256, 0, stream>>>(
        at, ca_Wo + (size_t)l * 65536, ca_bo + l * 256, A, Bb, M, 256, 256, 0, 0,
        nullptr, nullptr, nullptr, nullptr, 1, 0);
    k_ln<<<M, 256, 0, stream>>>(Bb, ln2_w + l * 256, ln2_b + l * 256, A);
    k_gemm_mf<<<dim3(FFD / 64, M / 128), 256, 0, stream>>>(
        A, ff1_W + (size_t)l * FFD * 256, ff1_b + l * FFD, nullptr, hb,
        M, FFD, 256, 1, 0, nullptr, nullptr, nullptr, nullptr, 1, 0);
    k_gemm_mf<<<dim3(256 / 64, M / 128), 256, 0, stream>>>(
        hb, ff2_W + (size_t)l * 256 * FFD, ff2_b + l * 256, A, Bb, M, 256, FFD, 0, 0,
        nullptr, nullptr, nullptr, nullptr, 1, 0);
    k_ln<<<M, 256, 0, stream>>>(Bb, ln3_w + l * 256, ln3_b + l * 256, A);
  };

  // ---- prefill over past 50 positions ----
  k_prepack<<<1536, 256, 0, stream>>>(ca_Wqkv, ca_bqkv, Wckv, bckv);
  k_embed<<<(int)Mpre, 256, 0, stream>>>(past, in_W, in_b, pos_emb, ln0_w, ln0_b, A);
  k_gemm_mf<<<dim3(1536 / 64, (int)Mpre / 128), 256, 0, stream>>>(
      A, Wckv, bckv, nullptr, nullptr, (int)Mpre, 1536, 256, 0, 2,
      nullptr, nullptr, nullptr, C6, PAST_N, 0);
  for (int l = 0; l < LAYERS; l++) layer(l, (int)Mpre, PAST_N, 0);
  k_readout<<<BATCH, 64, 0, stream>>>(A, out_W, out_b, past, cur, ndb, out, PAST_N, 0, 1);

  // ---- pack decode weight stream (into A scratch, dead after prefill) ----
  k_pack_stream<<<(TOTAL_ENT + 255) / 256, 256, 0, stream>>>(
      sa_Wqkv, sa_Wo, ca_Wqkv, ca_Wo, ff1_W, ff2_W, Wd);

  // ---- fused 19-step decode: one WG per batch element ----
  k_decode<<<BATCH, NT, 0, stream>>>(
      Wd, bckv, in_W, in_b, pos_emb, ln0_w, ln0_b,
      sa_bqkv, sa_bo, ca_bqkv, ca_bo, ff1_b, ff2_b,
      ln1_w, ln1_b, ln2_w, ln2_b, ln3_w, ln3_b,
      out_W, out_b, Ksa, Vsa, C6, ndb, cur, out);
}